// Round 1
// baseline (168.499 us; speedup 1.0000x reference)
//
#include <hip/hip_runtime.h>
#include <math.h>

// SoftVoxelOccupancyVFE: per-voxel masked mean/var of xyz + tiny MLP + sigmoid.
// N=200000 voxels, M=32 points, C=4 channels interleaved. Memory-bound
// (~103 MB fetch floor ~= 16.5 us @ 6.3 TB/s).
//
// v2: fully-contiguous wave streaming. Previous layout (4 lanes/voxel,
// lane t -> (t>>2)*512 + ((t&3)+4i)*16) made each wave64 load touch 16
// scattered 64B segments over an 8KB span (2x TA/L2 requests, split 128B
// lines). Now a wave owns 16 consecutive voxels and load i reads flat
// element i*64+lane: 64 lanes x 16B = 1KB dense per instruction (the m13
// 6.3TB/s copy pattern). Ownership falls out as: iteration i covers voxels
// 2i (lanes 0-31) and 2i+1 (lanes 32-63), point index p = lane&31 fixed.
// Per-iteration 5-level half-wave butterfly -> lane p==i keeps voxel totals.
// Shuffle count per voxel is unchanged vs v1 (10 DS-ops/voxel).

typedef float floatx4 __attribute__((ext_vector_type(4)));

#define VOX_PER_WAVE 16
#define WAVES_PER_BLOCK 4
#define VOX_PER_BLOCK 64   // 256 threads / 64 lanes * 16 vox

__global__ __launch_bounds__(256) void vfe_kernel(
    const floatx4* __restrict__ feats,     // N*32 float4 (x,y,z,w)
    const int*    __restrict__ num_points, // N
    const float*  __restrict__ W1,         // 5x16 row-major
    const float*  __restrict__ b1,         // 16
    const float*  __restrict__ W2,         // 16x1
    const float*  __restrict__ b2,         // 1
    float*        __restrict__ out,        // N
    int N)
{
    __shared__ float sW1[80];
    __shared__ float sb1[16];
    __shared__ float sW2[16];
    __shared__ float sb2;

    const int t = threadIdx.x;
    if (t < 80) sW1[t] = W1[t];
    if (t < 16) { sb1[t] = b1[t]; sW2[t] = W2[t]; }
    if (t == 0) sb2 = b2[0];
    __syncthreads();

    const int lane = t & 63;
    const int wave = t >> 6;
    const int h    = lane >> 5;   // half: which of the 2 voxels this iter
    const int p    = lane & 31;   // point index (fixed per lane)
    const int tile = (blockIdx.x * WAVES_PER_BLOCK + wave) * VOX_PER_WAVE;
    if (tile >= N) return;

    const floatx4* base = feats + (size_t)tile * 32;

    floatx4 f[8];
    int     npv[8];
    const bool full = (tile + VOX_PER_WAVE <= N);
    if (full) {
        // 8 dense nontemporal 1KB wave-loads; issue all before consuming.
        #pragma unroll
        for (int i = 0; i < 8; ++i)
            f[i] = __builtin_nontemporal_load(&base[i * 64 + lane]);
        // voxel for iteration i is tile + 2i + h (64B/wave, L1-resident)
        #pragma unroll
        for (int i = 0; i < 8; ++i)
            npv[i] = num_points[tile + 2 * i + h];
    } else {
        #pragma unroll
        for (int i = 0; i < 8; ++i) {
            const int v = tile + 2 * i + h;   // voxel covered by element i*64+lane
            if (v < N) {
                f[i]   = base[i * 64 + lane];
                npv[i] = num_points[v];
            } else {
                f[i]   = (floatx4){0.0f, 0.0f, 0.0f, 0.0f};
                npv[i] = 0;
            }
        }
    }

    // keeper registers: lane p==i (in each half) owns voxel tile+2i+h
    float KX = 0.0f, KY = 0.0f, KZ = 0.0f, KQ = 0.0f;
    int   KNP = 0;

    #pragma unroll
    for (int i = 0; i < 8; ++i) {
        const float m  = (p < npv[i]) ? 1.0f : 0.0f;
        float sx = f[i].x * m;
        float sy = f[i].y * m;
        float sz = f[i].z * m;
        float sq = m * (f[i].x * f[i].x + f[i].y * f[i].y + f[i].z * f[i].z);
        // 5-level butterfly; xor masks 1..16 stay inside each 32-lane half
        #pragma unroll
        for (int d = 1; d <= 16; d <<= 1) {
            sx += __shfl_xor(sx, d);
            sy += __shfl_xor(sy, d);
            sz += __shfl_xor(sz, d);
            sq += __shfl_xor(sq, d);
        }
        if (p == i) { KX = sx; KY = sy; KZ = sz; KQ = sq; KNP = npv[i]; }
    }

    // lanes p<8 each finalize one voxel: vox = tile + 2p + h
    if (p < 8) {
        const int vox = tile + 2 * p + h;
        if (vox < N) {
            const float npf       = (float)KNP;
            const float inv_denom = 1.0f / fmaxf(npf, 1.0f);

            const float mean_x = KX * inv_denom;
            const float mean_y = KY * inv_denom;
            const float mean_z = KZ * inv_denom;

            // sum m*(x-mx)^2 etc = KQ - (KX^2+KY^2+KZ^2)/denom (exact; 0 for np=0)
            const float qtot     = KQ - (KX * KX + KY * KY + KZ * KZ) * inv_denom;
            const float var_mean = fmaxf(qtot, 0.0f) * inv_denom * (1.0f / 3.0f);

            const float p_var     = __expf(-0.5f * var_mean);
            const float p_density = fminf(npf, 10.0f) * 0.1f;

            // full 16-unit MLP in one lane; uniform LDS index -> broadcast reads
            float c = sb2;
            #pragma unroll
            for (int u = 0; u < 16; ++u) {
                float hu = sb1[u]
                         + p_density * sW1[u]
                         + p_var     * sW1[16 + u]
                         + mean_x    * sW1[32 + u]
                         + mean_y    * sW1[48 + u]
                         + mean_z    * sW1[64 + u];
                c += fmaxf(hu, 0.0f) * sW2[u];
            }
            out[vox] = 1.0f / (1.0f + __expf(-c));
        }
    }
}

extern "C" void kernel_launch(void* const* d_in, const int* in_sizes, int n_in,
                              void* d_out, int out_size, void* d_ws, size_t ws_size,
                              hipStream_t stream) {
    // setup_inputs order: features, num_points, coors, W1, b1, W2, b2
    const floatx4* feats     = (const floatx4*)d_in[0];
    const int*    num_points = (const int*)d_in[1];
    // d_in[2] = coors (unused by the reference)
    const float*  W1 = (const float*)d_in[3];
    const float*  b1 = (const float*)d_in[4];
    const float*  W2 = (const float*)d_in[5];
    const float*  b2 = (const float*)d_in[6];
    float* out = (float*)d_out;

    const int N = in_sizes[1];                 // 200000
    const int blocks = (N + VOX_PER_BLOCK - 1) / VOX_PER_BLOCK;
    vfe_kernel<<<blocks, 256, 0, stream>>>(feats, num_points, W1, b1, W2, b2, out, N);
}

// Round 4
// 155.886 us; speedup vs baseline: 1.0809x; 1.0809x over previous
//
#include <hip/hip_runtime.h>
#include <math.h>

// SoftVoxelOccupancyVFE: per-voxel masked mean/var of xyz + tiny MLP + sigmoid.
// N=200000 voxels, M=32 points, C=4 channels interleaved. Memory-bound
// (~103 MB fetch floor ~= 16.5 us @ 6.3 TB/s).
//
// v4: contiguous streaming + reg-staged LDS transpose. (v3 used
// __builtin_amdgcn_global_load_lds and the container died twice with no
// kernel signal; v4 holds the same hypothesis using only constructs proven
// in passing runs: nontemporal vector loads, ds_write/ds_read, shuffles.)
//  - Global loads are PERFECTLY LINEAR: element e = i*64+lane of the wave's
//    16-voxel (8KB) tile -> 8 dense 1KB wave-instructions (m13 copy pattern).
//    v1's pattern was 16 scattered 64B segments per instruction (2x TA work).
//  - Transpose happens via the LDS write address, swizzled with the
//    involution slot = p ^ ((v&1)<<2). Derivation: compute-phase ds_read_b128
//    has thread (j=t&3, vloc=t>>2) reading point p=j+4i; at 8-lane phase
//    granularity the 4-bank group index becomes (j0, j1, i0^v0) -> bijective
//    -> 8 distinct groups -> conflict-free. Write side maps each 16-slot run
//    onto itself -> also conflict-free. (v3's p^(v&7) left bank-group bit 2
//    constant per quarter-wave -> residual 4-way; fixed here.)
//  - Compute phase identical to v1 (best passing: 150.9/154.5 us):
//    4 lanes/voxel, one 2-level shuffle reduce, split MLP.

typedef float floatx4 __attribute__((ext_vector_type(4)));

#define VOX_PER_BLOCK 64   // 256 threads = 4 waves x 16 voxels

__global__ __launch_bounds__(256) void vfe_kernel(
    const floatx4* __restrict__ feats,     // N*32 float4 (x,y,z,w)
    const int*    __restrict__ num_points, // N
    const float*  __restrict__ W1,         // 5x16 row-major
    const float*  __restrict__ b1,         // 16
    const float*  __restrict__ W2,         // 16x1
    const float*  __restrict__ b2,         // 1
    float*        __restrict__ out,        // N
    int N)
{
    __shared__ floatx4 sfeat[VOX_PER_BLOCK * 32];   // 32 KB, swizzled rows
    __shared__ float sW1[80];
    __shared__ float sb1[16];
    __shared__ float sW2[16];
    __shared__ float sb2;

    const int t = threadIdx.x;
    if (t < 80) sW1[t] = W1[t];
    if (t < 16) { sb1[t] = b1[t]; sW2[t] = W2[t]; }
    if (t == 0) sb2 = b2[0];

    const int lane = t & 63;
    const int wave = t >> 6;
    const int tileVox = blockIdx.x * VOX_PER_BLOCK;
    const int wtile   = tileVox + wave * 16;        // this wave's 16 voxels

    floatx4* slds = sfeat + wave * 16 * 32;         // wave's 8KB region

    // ---- stage: 8 dense 1KB wave-loads, then swizzled ds_writes ----
    floatx4 val[8];
    if (wtile + 16 <= N) {
        #pragma unroll
        for (int i = 0; i < 8; ++i)
            val[i] = __builtin_nontemporal_load(
                        feats + ((size_t)wtile * 32 + i * 64 + lane));
    } else {
        // tail tile (unused when N % 64 == 0): guarded loads
        #pragma unroll
        for (int i = 0; i < 8; ++i) {
            const int e = i * 64 + lane;
            val[i] = (floatx4){0.0f, 0.0f, 0.0f, 0.0f};
            if (wtile + (e >> 5) < N)
                val[i] = feats[(size_t)wtile * 32 + e];
        }
    }
    #pragma unroll
    for (int i = 0; i < 8; ++i) {
        const int e = i * 64 + lane;
        const int v = e >> 5;                   // voxel within wave tile
        const int p = e & 31;                   // point index
        slds[v * 32 + (p ^ ((v & 1) << 2))] = val[i];
    }
    __syncthreads();

    // ---- compute phase: v1 layout, 4 lanes per voxel ----
    const int j    = t & 3;
    const int vloc = t >> 2;                 // block-local voxel 0..63
    const int vox  = tileVox + vloc;
    if (vox >= N) return;                    // no barriers past this point

    const int   np        = num_points[vox];
    const float npf       = (float)np;
    const float inv_denom = 1.0f / fmaxf(npf, 1.0f);

    const floatx4* vrow = sfeat + vloc * 32;
    const int      swz  = (vloc & 1) << 2;   // matches staging involution

    float sx = 0.0f, sy = 0.0f, sz = 0.0f, sq = 0.0f;
    #pragma unroll
    for (int i = 0; i < 8; ++i) {
        const int p = j + 4 * i;
        const floatx4 f = vrow[p ^ swz];
        const float m = (p < np) ? 1.0f : 0.0f;
        sx += f.x * m;
        sy += f.y * m;
        sz += f.z * m;
        sq += m * (f.x * f.x + f.y * f.y + f.z * f.z);
    }

    // single 2-level reduction over the 4-lane group (xor masks stay in-group)
    #pragma unroll
    for (int d = 1; d <= 2; d <<= 1) {
        sx += __shfl_xor(sx, d);
        sy += __shfl_xor(sy, d);
        sz += __shfl_xor(sz, d);
        sq += __shfl_xor(sq, d);
    }

    const float mean_x = sx * inv_denom;
    const float mean_y = sy * inv_denom;
    const float mean_z = sz * inv_denom;

    // sum m*(x-mx)^2 etc = sq - (sx^2+sy^2+sz^2)/denom  (exact; 0 for np=0)
    const float qtot     = sq - (sx * sx + sy * sy + sz * sz) * inv_denom;
    const float var_mean = fmaxf(qtot, 0.0f) * inv_denom * (1.0f / 3.0f);

    const float p_var     = __expf(-0.5f * var_mean);
    const float p_density = fminf(npf, 10.0f) * 0.1f;

    // MLP: lane j computes hidden units j, j+4, j+8, j+12; 2-level reduce
    float c = 0.0f;
    #pragma unroll
    for (int u0 = 0; u0 < 16; u0 += 4) {
        const int u = u0 + j;
        float h = sb1[u]
                + p_density * sW1[u]
                + p_var     * sW1[16 + u]
                + mean_x    * sW1[32 + u]
                + mean_y    * sW1[48 + u]
                + mean_z    * sW1[64 + u];
        c += fmaxf(h, 0.0f) * sW2[u];
    }
    c += __shfl_xor(c, 1);
    c += __shfl_xor(c, 2);

    if (j == 0) {
        const float logit = c + sb2;
        out[vox] = 1.0f / (1.0f + __expf(-logit));
    }
}

extern "C" void kernel_launch(void* const* d_in, const int* in_sizes, int n_in,
                              void* d_out, int out_size, void* d_ws, size_t ws_size,
                              hipStream_t stream) {
    // setup_inputs order: features, num_points, coors, W1, b1, W2, b2
    const floatx4* feats     = (const floatx4*)d_in[0];
    const int*    num_points = (const int*)d_in[1];
    // d_in[2] = coors (unused by the reference)
    const float*  W1 = (const float*)d_in[3];
    const float*  b1 = (const float*)d_in[4];
    const float*  W2 = (const float*)d_in[5];
    const float*  b2 = (const float*)d_in[6];
    float* out = (float*)d_out;

    const int N = in_sizes[1];                 // 200000
    const int blocks = (N + VOX_PER_BLOCK - 1) / VOX_PER_BLOCK;
    vfe_kernel<<<blocks, 256, 0, stream>>>(feats, num_points, W1, b1, W2, b2, out, N);
}